// Round 2
// baseline (300.819 us; speedup 1.0000x reference)
//
#include <hip/hip_runtime.h>
#include <stdint.h>

#define NSEL 300
#define BB 2
#define QQ 900
#define CC 91
#define NQC (QQ * CC)   // 81900
#define MH 128
#define MW 128
#define TGT 512

#define NBUCKET 4096
#define CAND_CAP 4096

// ---------------- Kernel 1: top-k + boxes/labels/uncertainty ----------------
__global__ __launch_bounds__(1024) void topk_kernel(
    const float* __restrict__ logits,    // [B,Q,C]
    const float* __restrict__ boxes_in,  // [B,Q,4]
    const float* __restrict__ logvars,   // [B,Q,4]
    const int*   __restrict__ tsizes,    // [B,2]
    float* __restrict__ out,             // full output buffer (float32)
    int*   __restrict__ sel)             // [B*NSEL] selected q indices
{
    __shared__ uint32_t hist[NBUCKET];
    __shared__ uint32_t scan[1024];
    __shared__ unsigned long long cand[CAND_CAP];
    __shared__ int s_count;
    __shared__ int s_cut;

    const int b   = blockIdx.x;
    const int tid = threadIdx.x;
    const float* lg = logits + (size_t)b * NQC;

    for (int i = tid; i < NBUCKET; i += 1024) hist[i] = 0u;
    if (tid == 0) s_count = 0;
    __syncthreads();

    // Pass 1: histogram of prob-key top bits. prob in (0,1] -> bits monotonic.
    for (int i = tid; i < NQC; i += 1024) {
        float x = lg[i];
        float p = 1.0f / (1.0f + expf(-x));
        uint32_t key = __float_as_uint(p);
        atomicAdd(&hist[key >> 18], 1u);
    }
    __syncthreads();

    // Parallel suffix scan to find cutoff bucket (replaces serial 4096-scan).
    {
        uint32_t part = hist[4 * tid] + hist[4 * tid + 1] +
                        hist[4 * tid + 2] + hist[4 * tid + 3];
        scan[tid] = part;
        __syncthreads();
        for (int off = 1; off < 1024; off <<= 1) {
            uint32_t v = scan[tid];
            if (tid + off < 1024) v += scan[tid + off];
            __syncthreads();
            scan[tid] = v;
            __syncthreads();
        }
        uint32_t sfx = scan[tid];
        uint32_t sfx_next = (tid < 1023) ? scan[tid + 1] : 0u;
        if (sfx >= NSEL && sfx_next < NSEL) {
            // crossing group == tid; refine to bucket granularity (<=4 steps)
            int acc = (int)sfx_next;
            int cut = 4 * tid;
            for (int bkt = 4 * tid + 3; bkt >= 4 * tid; --bkt) {
                acc += (int)hist[bkt];
                if (acc >= NSEL) { cut = bkt; break; }
            }
            s_cut = cut;
        }
    }
    __syncthreads();
    const uint32_t cut = (uint32_t)s_cut;

    // Pass 2: collect candidates (superset of the true top-300)
    for (int i = tid; i < NQC; i += 1024) {
        float x = lg[i];
        float p = 1.0f / (1.0f + expf(-x));
        uint32_t key = __float_as_uint(p);
        if ((key >> 18) >= cut) {
            int pos = atomicAdd(&s_count, 1);
            if (pos < CAND_CAP) {
                // composite: high = prob bits, low = ~index  (desc sort =>
                // higher prob first; equal prob => lower index, like lax.top_k)
                cand[pos] = ((unsigned long long)key << 32) | (uint32_t)(~(uint32_t)i);
            }
        }
    }
    __syncthreads();

    int count = s_count;
    if (count > CAND_CAP) count = CAND_CAP;
    int P = 512;
    while (P < count) P <<= 1;
    for (int i = count + tid; i < P; i += 1024) cand[i] = 0ull;  // pads sort last
    __syncthreads();

    // Bitonic sort, descending
    for (int k = 2; k <= P; k <<= 1) {
        for (int j = k >> 1; j > 0; j >>= 1) {
            for (int i = tid; i < P; i += 1024) {
                int l = i ^ j;
                if (l > i) {
                    unsigned long long a = cand[i];
                    unsigned long long c2 = cand[l];
                    bool up = ((i & k) == 0);   // descending order
                    if ((a < c2) == up) { cand[i] = c2; cand[l] = a; }
                }
            }
            __syncthreads();
        }
    }

    // Epilogue: emit small outputs
    float* out_scores = out;                 // [B*NSEL]
    float* out_labels = out + 600;           // [B*NSEL]
    float* out_boxes  = out + 1200;          // [B*NSEL*4]
    float* out_unc    = out + 3600;          // [B*NSEL]

    if (tid < NSEL) {
        unsigned long long e = cand[tid];
        uint32_t key = (uint32_t)(e >> 32);
        uint32_t idx = ~((uint32_t)(e & 0xFFFFFFFFull));
        int q = (int)(idx / CC);
        int label = (int)(idx - (uint32_t)q * CC);
        int o = b * NSEL + tid;

        out_scores[o] = __uint_as_float(key);
        out_labels[o] = (float)label;

        const float* bx = boxes_in + ((size_t)(b * QQ + q)) * 4;
        float cx = bx[0], cy = bx[1], w = bx[2], h = bx[3];
        float hh = (float)tsizes[b * 2 + 0];
        float ww = (float)tsizes[b * 2 + 1];
        out_boxes[o * 4 + 0] = (cx - 0.5f * w) * ww;
        out_boxes[o * 4 + 1] = (cy - 0.5f * h) * hh;
        out_boxes[o * 4 + 2] = (cx + 0.5f * w) * ww;
        out_boxes[o * 4 + 3] = (cy + 0.5f * h) * hh;

        const float* gv = logvars + ((size_t)(b * QQ + q)) * 4;
        float s0 = gv[0] + gv[1];
        float s1 = s0 + gv[2];
        float s2 = s1 + gv[3];
        out_unc[o] = s2 * 0.25f;

        sel[o] = q;
    }
}

// ---------------- Kernel 2: bilinear upsample 128->512 + threshold ----------
// jax.image.resize bilinear (half-pixel): x_in = x*0.25 - 0.375
// Edge normalization == weight-1 clamp. Vertical first, then horizontal,
// one rounding per op (no FMA) to match the reference contraction.
// Dyadic 4-phase weights; every pixel's FP expression bit-identical to the
// previously passing per-pixel version.
__global__ __launch_bounds__(256) void mask_kernel(
    const float* __restrict__ masks_in,  // [B,Q,128,128]
    const int*   __restrict__ sel,       // [B*NSEL]
    float* __restrict__ out_masks)       // [B*NSEL,512,512]
{
    const int m     = blockIdx.x;        // 0..599
    const int b     = m / NSEL;
    const int ytile = blockIdx.y;        // 0..7 -> 64 output rows each
    const int q     = sel[m];

    const float* src = masks_in + ((size_t)(b * QQ + q)) * (MH * MW);
    float* dst = out_masks + (size_t)m * (TGT * TGT);

    const int y0 = ytile * 64;
    int r_lo = (int)floorf((float)y0 * 0.25f - 0.375f);
    if (r_lo < 0) r_lo = 0;
    int r_hi = (int)floorf((float)(y0 + 63) * 0.25f - 0.375f) + 1;
    if (r_hi > MH - 1) r_hi = MH - 1;
    const int nrows = r_hi - r_lo + 1;   // <= 18

    __shared__ float4 S4[18 * (MW / 4)];
    float* S = (float*)S4;
    {
        const float4* src4 = (const float4*)(src + (size_t)r_lo * MW);
        const int n4 = nrows * (MW / 4);
        for (int i = threadIdx.x; i < n4; i += 256) S4[i] = src4[i];
    }
    __syncthreads();

    const int xg = threadIdx.x & 127;    // column group: output cols 4xg..4xg+3
    const int rh = threadIdx.x >> 7;     // row half (0/1)
    const int cm1 = (xg == 0)   ? 0   : xg - 1;
    const int cp1 = (xg == 127) ? 127 : xg + 1;

    for (int i = 0; i < 32; ++i) {
        const int y = y0 + rh * 32 + i;
        float yin = (float)y * 0.25f - 0.375f;   // exact in f32
        int r0 = (int)floorf(yin);
        float fy = yin - (float)r0;
        int r1 = r0 + 1;
        if (r0 < 0)           { r0 = 0;      r1 = 0;      fy = 0.0f; }
        else if (r1 > MH - 1) { r0 = MH - 1; r1 = MH - 1; fy = 0.0f; }
        const float wy0 = 1.0f - fy;
        const float wy1 = fy;
        const float* Ra = S + (size_t)(r0 - r_lo) * MW;
        const float* Rb = S + (size_t)(r1 - r_lo) * MW;

        // three vertical blends (per-op rounding)
        float tm1 = __fadd_rn(__fmul_rn(wy0, Ra[cm1]), __fmul_rn(wy1, Rb[cm1]));
        float tc  = __fadd_rn(__fmul_rn(wy0, Ra[xg ]), __fmul_rn(wy1, Rb[xg ]));
        float tp1 = __fadd_rn(__fmul_rn(wy0, Ra[cp1]), __fmul_rn(wy1, Rb[cp1]));

        // horizontal: phases fx = {0.625, 0.875} from (tm1,tc),
        //             phases fx = {0.125, 0.375} from (tc,tp1)
        float v0, v1, v2, v3;
        if (xg == 0) {            // x=0,1: clamped -> exact tc (fx=0 path)
            v0 = tc; v1 = tc;
        } else {
            v0 = __fadd_rn(__fmul_rn(0.375f, tm1), __fmul_rn(0.625f, tc));
            v1 = __fadd_rn(__fmul_rn(0.125f, tm1), __fmul_rn(0.875f, tc));
        }
        if (xg == 127) {          // x=510,511: clamped -> exact tc
            v2 = tc; v3 = tc;
        } else {
            v2 = __fadd_rn(__fmul_rn(0.875f, tc), __fmul_rn(0.125f, tp1));
            v3 = __fadd_rn(__fmul_rn(0.625f, tc), __fmul_rn(0.375f, tp1));
        }

        float4 res;
        res.x = (v0 > 0.0f) ? 1.0f : 0.0f;
        res.y = (v1 > 0.0f) ? 1.0f : 0.0f;
        res.z = (v2 > 0.0f) ? 1.0f : 0.0f;
        res.w = (v3 > 0.0f) ? 1.0f : 0.0f;
        *reinterpret_cast<float4*>(&dst[(size_t)y * TGT + 4 * xg]) = res;
    }
}

extern "C" void kernel_launch(void* const* d_in, const int* in_sizes, int n_in,
                              void* d_out, int out_size, void* d_ws, size_t ws_size,
                              hipStream_t stream) {
    (void)in_sizes; (void)n_in; (void)out_size; (void)ws_size;

    const float* pred_logits  = (const float*)d_in[0];  // [2,900,91]
    const float* pred_boxes   = (const float*)d_in[1];  // [2,900,4]
    const float* pred_masks   = (const float*)d_in[2];  // [2,900,128,128]
    const float* pred_logvars = (const float*)d_in[3];  // [2,900,4]
    const int*   target_sizes = (const int*)d_in[4];    // [2,2]

    float* out = (float*)d_out;
    int*   sel = (int*)d_ws;                            // 600 ints

    hipLaunchKernelGGL(topk_kernel, dim3(BB), dim3(1024), 0, stream,
                       pred_logits, pred_boxes, pred_logvars, target_sizes,
                       out, sel);

    float* out_masks = out + 4200;  // after scores/labels/boxes/uncertainty
    hipLaunchKernelGGL(mask_kernel, dim3(BB * NSEL, 8), dim3(256), 0, stream,
                       pred_masks, sel, out_masks);
}

// Round 3
// 264.311 us; speedup vs baseline: 1.1381x; 1.1381x over previous
//
#include <hip/hip_runtime.h>
#include <stdint.h>

#define NSEL 300
#define BB 2
#define QQ 900
#define CC 91
#define NQC (QQ * CC)   // 81900
#define MH 128
#define MW 128
#define TGT 512

#define NBUCKET 4096
#define CAND_CAP 4096
#define NCHUNK 16                 // chunks per batch
#define CHUNK 5119                // ceil(81900/16)

// ---- d_ws byte offsets ----
#define WS_CAND   0               // u64 [2][4096]   (65536 B)
#define WS_KEYS   65536           // u32 [2][81900]  (655200 B)
#define WS_PART   720896          // u32 [32][4096]  (524288 B)
#define WS_SEL    1245184         // int [600]
#define WS_CUT    1247584         // u32 [2]
#define WS_COUNT  1247592         // int [2]

// ---------------- K1: keys + per-block histogram partials ----------------
__global__ __launch_bounds__(256) void hist_kernel(
    const float* __restrict__ logits, uint8_t* __restrict__ ws)
{
    __shared__ uint32_t hist[NBUCKET];
    const int blk   = blockIdx.x;          // 0..31
    const int b     = blk >> 4;
    const int chunk = blk & 15;

    uint32_t* keys = (uint32_t*)(ws + WS_KEYS) + (size_t)b * NQC;
    uint32_t* part = (uint32_t*)(ws + WS_PART) + (size_t)blk * NBUCKET;

    for (int i = threadIdx.x; i < NBUCKET; i += 256) hist[i] = 0u;
    __syncthreads();

    const int base = chunk * CHUNK;
    int end = base + CHUNK; if (end > NQC) end = NQC;
    const float* lg = logits + (size_t)b * NQC;

    for (int i = base + threadIdx.x; i < end; i += 256) {
        float x = lg[i];
        float p = 1.0f / (1.0f + expf(-x));      // identical expression
        uint32_t key = __float_as_uint(p);
        keys[i] = key;
        atomicAdd(&hist[key >> 18], 1u);
    }
    __syncthreads();

    for (int i = threadIdx.x; i < NBUCKET; i += 256) part[i] = hist[i];
}

// ---------------- K2: reduce partials + suffix scan -> cut ----------------
__global__ __launch_bounds__(1024) void scan_kernel(uint8_t* __restrict__ ws)
{
    __shared__ uint32_t hist[NBUCKET];
    __shared__ uint32_t scan[1024];
    __shared__ int s_cut;

    const int b   = blockIdx.x;
    const int tid = threadIdx.x;
    const uint32_t* part = (const uint32_t*)(ws + WS_PART)
                         + (size_t)b * NCHUNK * NBUCKET;

    for (int j = tid; j < NBUCKET; j += 1024) {
        uint32_t s = 0;
        #pragma unroll
        for (int p = 0; p < NCHUNK; ++p) s += part[(size_t)p * NBUCKET + j];
        hist[j] = s;
    }
    __syncthreads();

    uint32_t partsum = hist[4 * tid] + hist[4 * tid + 1] +
                       hist[4 * tid + 2] + hist[4 * tid + 3];
    scan[tid] = partsum;
    __syncthreads();
    for (int off = 1; off < 1024; off <<= 1) {
        uint32_t v = scan[tid];
        if (tid + off < 1024) v += scan[tid + off];
        __syncthreads();
        scan[tid] = v;
        __syncthreads();
    }
    uint32_t sfx = scan[tid];
    uint32_t sfx_next = (tid < 1023) ? scan[tid + 1] : 0u;
    if (sfx >= NSEL && sfx_next < NSEL) {
        int acc = (int)sfx_next;
        int cut = 4 * tid;
        for (int bkt = 4 * tid + 3; bkt >= 4 * tid; --bkt) {
            acc += (int)hist[bkt];
            if (acc >= NSEL) { cut = bkt; break; }
        }
        s_cut = cut;
    }
    __syncthreads();
    if (tid == 0) {
        ((uint32_t*)(ws + WS_CUT))[b] = (uint32_t)s_cut;
        ((int*)(ws + WS_COUNT))[b] = 0;
    }
}

// ---------------- K3: collect candidates >= cut ----------------
__global__ __launch_bounds__(256) void collect_kernel(uint8_t* __restrict__ ws)
{
    const int blk   = blockIdx.x;          // 0..31
    const int b     = blk >> 4;
    const int chunk = blk & 15;

    const uint32_t cut = ((const uint32_t*)(ws + WS_CUT))[b];
    const uint32_t* keys = (const uint32_t*)(ws + WS_KEYS) + (size_t)b * NQC;
    unsigned long long* cand = (unsigned long long*)(ws + WS_CAND)
                             + (size_t)b * CAND_CAP;
    int* count = (int*)(ws + WS_COUNT);

    const int base = chunk * CHUNK;
    int end = base + CHUNK; if (end > NQC) end = NQC;

    for (int i = base + threadIdx.x; i < end; i += 256) {
        uint32_t key = keys[i];
        if ((key >> 18) >= cut) {
            int pos = atomicAdd(&count[b], 1);
            if (pos < CAND_CAP) {
                cand[pos] = ((unsigned long long)key << 32)
                          | (uint32_t)(~(uint32_t)i);
            }
        }
    }
}

// ---------------- K4: sort candidates + epilogue ----------------
__global__ __launch_bounds__(1024) void sort_kernel(
    const float* __restrict__ boxes_in,  // [B,Q,4]
    const float* __restrict__ logvars,   // [B,Q,4]
    const int*   __restrict__ tsizes,    // [B,2]
    float* __restrict__ out,
    uint8_t* __restrict__ ws)
{
    __shared__ unsigned long long cand[CAND_CAP];

    const int b   = blockIdx.x;
    const int tid = threadIdx.x;

    const unsigned long long* gcand = (const unsigned long long*)(ws + WS_CAND)
                                    + (size_t)b * CAND_CAP;
    int count = ((const int*)(ws + WS_COUNT))[b];
    if (count > CAND_CAP) count = CAND_CAP;

    int P = 512;
    while (P < count) P <<= 1;

    for (int i = tid; i < P; i += 1024)
        cand[i] = (i < count) ? gcand[i] : 0ull;
    __syncthreads();

    // Bitonic sort, descending; ties -> lower index first (low word = ~index)
    for (int k = 2; k <= P; k <<= 1) {
        for (int j = k >> 1; j > 0; j >>= 1) {
            for (int i = tid; i < P; i += 1024) {
                int l = i ^ j;
                if (l > i) {
                    unsigned long long a = cand[i];
                    unsigned long long c2 = cand[l];
                    bool up = ((i & k) == 0);
                    if ((a < c2) == up) { cand[i] = c2; cand[l] = a; }
                }
            }
            __syncthreads();
        }
    }

    float* out_scores = out;                 // [B*NSEL]
    float* out_labels = out + 600;
    float* out_boxes  = out + 1200;
    float* out_unc    = out + 3600;
    int*   sel        = (int*)(ws + WS_SEL);

    if (tid < NSEL) {
        unsigned long long e = cand[tid];
        uint32_t key = (uint32_t)(e >> 32);
        uint32_t idx = ~((uint32_t)(e & 0xFFFFFFFFull));
        int q = (int)(idx / CC);
        int label = (int)(idx - (uint32_t)q * CC);
        int o = b * NSEL + tid;

        out_scores[o] = __uint_as_float(key);
        out_labels[o] = (float)label;

        const float* bx = boxes_in + ((size_t)(b * QQ + q)) * 4;
        float cx = bx[0], cy = bx[1], w = bx[2], h = bx[3];
        float hh = (float)tsizes[b * 2 + 0];
        float ww = (float)tsizes[b * 2 + 1];
        out_boxes[o * 4 + 0] = (cx - 0.5f * w) * ww;
        out_boxes[o * 4 + 1] = (cy - 0.5f * h) * hh;
        out_boxes[o * 4 + 2] = (cx + 0.5f * w) * ww;
        out_boxes[o * 4 + 3] = (cy + 0.5f * h) * hh;

        const float* gv = logvars + ((size_t)(b * QQ + q)) * 4;
        float s0 = gv[0] + gv[1];
        float s1 = s0 + gv[2];
        float s2 = s1 + gv[3];
        out_unc[o] = s2 * 0.25f;

        sel[o] = q;
    }
}

// ---------------- K5: bilinear upsample 128->512 + threshold ----------
// Byte-identical numerics/structure to round-2 version.
__global__ __launch_bounds__(256) void mask_kernel(
    const float* __restrict__ masks_in,  // [B,Q,128,128]
    const int*   __restrict__ sel,       // [B*NSEL]
    float* __restrict__ out_masks)       // [B*NSEL,512,512]
{
    const int m     = blockIdx.x;        // 0..599
    const int b     = m / NSEL;
    const int ytile = blockIdx.y;        // 0..7 -> 64 output rows each
    const int q     = sel[m];

    const float* src = masks_in + ((size_t)(b * QQ + q)) * (MH * MW);
    float* dst = out_masks + (size_t)m * (TGT * TGT);

    const int y0 = ytile * 64;
    int r_lo = (int)floorf((float)y0 * 0.25f - 0.375f);
    if (r_lo < 0) r_lo = 0;
    int r_hi = (int)floorf((float)(y0 + 63) * 0.25f - 0.375f) + 1;
    if (r_hi > MH - 1) r_hi = MH - 1;
    const int nrows = r_hi - r_lo + 1;   // <= 18

    __shared__ float4 S4[18 * (MW / 4)];
    float* S = (float*)S4;
    {
        const float4* src4 = (const float4*)(src + (size_t)r_lo * MW);
        const int n4 = nrows * (MW / 4);
        for (int i = threadIdx.x; i < n4; i += 256) S4[i] = src4[i];
    }
    __syncthreads();

    const int xg = threadIdx.x & 127;    // output cols 4xg..4xg+3
    const int rh = threadIdx.x >> 7;     // row half (0/1)
    const int cm1 = (xg == 0)   ? 0   : xg - 1;
    const int cp1 = (xg == 127) ? 127 : xg + 1;

    for (int i = 0; i < 32; ++i) {
        const int y = y0 + rh * 32 + i;
        float yin = (float)y * 0.25f - 0.375f;
        int r0 = (int)floorf(yin);
        float fy = yin - (float)r0;
        int r1 = r0 + 1;
        if (r0 < 0)           { r0 = 0;      r1 = 0;      fy = 0.0f; }
        else if (r1 > MH - 1) { r0 = MH - 1; r1 = MH - 1; fy = 0.0f; }
        const float wy0 = 1.0f - fy;
        const float wy1 = fy;
        const float* Ra = S + (size_t)(r0 - r_lo) * MW;
        const float* Rb = S + (size_t)(r1 - r_lo) * MW;

        float tm1 = __fadd_rn(__fmul_rn(wy0, Ra[cm1]), __fmul_rn(wy1, Rb[cm1]));
        float tc  = __fadd_rn(__fmul_rn(wy0, Ra[xg ]), __fmul_rn(wy1, Rb[xg ]));
        float tp1 = __fadd_rn(__fmul_rn(wy0, Ra[cp1]), __fmul_rn(wy1, Rb[cp1]));

        float v0, v1, v2, v3;
        if (xg == 0) {
            v0 = tc; v1 = tc;
        } else {
            v0 = __fadd_rn(__fmul_rn(0.375f, tm1), __fmul_rn(0.625f, tc));
            v1 = __fadd_rn(__fmul_rn(0.125f, tm1), __fmul_rn(0.875f, tc));
        }
        if (xg == 127) {
            v2 = tc; v3 = tc;
        } else {
            v2 = __fadd_rn(__fmul_rn(0.875f, tc), __fmul_rn(0.125f, tp1));
            v3 = __fadd_rn(__fmul_rn(0.625f, tc), __fmul_rn(0.375f, tp1));
        }

        float4 res;
        res.x = (v0 > 0.0f) ? 1.0f : 0.0f;
        res.y = (v1 > 0.0f) ? 1.0f : 0.0f;
        res.z = (v2 > 0.0f) ? 1.0f : 0.0f;
        res.w = (v3 > 0.0f) ? 1.0f : 0.0f;
        *reinterpret_cast<float4*>(&dst[(size_t)y * TGT + 4 * xg]) = res;
    }
}

extern "C" void kernel_launch(void* const* d_in, const int* in_sizes, int n_in,
                              void* d_out, int out_size, void* d_ws, size_t ws_size,
                              hipStream_t stream) {
    (void)in_sizes; (void)n_in; (void)out_size; (void)ws_size;

    const float* pred_logits  = (const float*)d_in[0];  // [2,900,91]
    const float* pred_boxes   = (const float*)d_in[1];  // [2,900,4]
    const float* pred_masks   = (const float*)d_in[2];  // [2,900,128,128]
    const float* pred_logvars = (const float*)d_in[3];  // [2,900,4]
    const int*   target_sizes = (const int*)d_in[4];    // [2,2]

    float*   out = (float*)d_out;
    uint8_t* ws  = (uint8_t*)d_ws;

    hipLaunchKernelGGL(hist_kernel, dim3(BB * NCHUNK), dim3(256), 0, stream,
                       pred_logits, ws);
    hipLaunchKernelGGL(scan_kernel, dim3(BB), dim3(1024), 0, stream, ws);
    hipLaunchKernelGGL(collect_kernel, dim3(BB * NCHUNK), dim3(256), 0, stream,
                       ws);
    hipLaunchKernelGGL(sort_kernel, dim3(BB), dim3(1024), 0, stream,
                       pred_boxes, pred_logvars, target_sizes, out, ws);

    float* out_masks = out + 4200;
    const int* sel = (const int*)(ws + WS_SEL);
    hipLaunchKernelGGL(mask_kernel, dim3(BB * NSEL, 8), dim3(256), 0, stream,
                       pred_masks, sel, out_masks);
}

// Round 5
// 219.748 us; speedup vs baseline: 1.3689x; 1.2028x over previous
//
#include <hip/hip_runtime.h>
#include <stdint.h>

#define NSEL 300
#define BB 2
#define QQ 900
#define CC 91
#define NQC (QQ * CC)   // 81900
#define MH 128
#define MW 128
#define TGT 512

#define NBUCKET 4096
#define CAND_CAP 4096
#define NCHUNK 16                 // chunks per batch
#define CHUNK 5119                // ceil(81900/16)

typedef float floatx4 __attribute__((ext_vector_type(4)));

// ---- d_ws byte offsets ----
#define WS_KEYS   0               // u32 [2][81900]  (655200 B, pad to 655360)
#define WS_PART   655360          // u32 [2][16][4096] (524288 B)
#define WS_SEL    1179648         // int [600]

// ---------------- K1: keys + per-block histogram partials ----------------
__global__ __launch_bounds__(256) void hist_kernel(
    const float* __restrict__ logits, uint8_t* __restrict__ ws)
{
    __shared__ uint32_t hist[NBUCKET];
    const int blk   = blockIdx.x;          // 0..31
    const int b     = blk >> 4;
    const int chunk = blk & 15;

    uint32_t* keys = (uint32_t*)(ws + WS_KEYS) + (size_t)b * NQC;
    uint32_t* part = (uint32_t*)(ws + WS_PART) + (size_t)blk * NBUCKET;

    for (int i = threadIdx.x; i < NBUCKET; i += 256) hist[i] = 0u;
    __syncthreads();

    const int base = chunk * CHUNK;
    int end = base + CHUNK; if (end > NQC) end = NQC;
    const float* lg = logits + (size_t)b * NQC;

    for (int i = base + threadIdx.x; i < end; i += 256) {
        float x = lg[i];
        float p = 1.0f / (1.0f + expf(-x));      // identical expression
        uint32_t key = __float_as_uint(p);
        keys[i] = key;
        atomicAdd(&hist[key >> 18], 1u);
    }
    __syncthreads();

    for (int i = threadIdx.x; i < NBUCKET; i += 256) part[i] = hist[i];
}

// -------- K2: reduce+scan (registers) + collect + rank-select + epilogue ----
__global__ __launch_bounds__(1024) void select_kernel(
    const float* __restrict__ boxes_in,  // [B,Q,4]
    const float* __restrict__ logvars,   // [B,Q,4]
    const int*   __restrict__ tsizes,    // [B,2]
    float* __restrict__ out,
    uint8_t* __restrict__ ws)
{
    __shared__ unsigned long long cand[CAND_CAP];
    __shared__ uint32_t wsum[16];
    __shared__ int s_count;
    __shared__ int s_cut;

    const int b    = blockIdx.x;
    const int tid  = threadIdx.x;
    const int lane = tid & 63;
    const int wid  = tid >> 6;

    if (tid == 0) s_count = 0;

    // Reduce 16 partial histograms; each thread owns buckets 4tid..4tid+3.
    const uint32_t* part = (const uint32_t*)(ws + WS_PART)
                         + (size_t)b * NCHUNK * NBUCKET;
    uint4 h = make_uint4(0u, 0u, 0u, 0u);
    #pragma unroll
    for (int p = 0; p < NCHUNK; ++p) {
        uint4 v = *(const uint4*)(part + (size_t)p * NBUCKET + 4 * tid);
        h.x += v.x; h.y += v.y; h.z += v.z; h.w += v.w;
    }
    const uint32_t val = h.x + h.y + h.z + h.w;

    // Wave-level reverse inclusive scan (suffix within wave).
    uint32_t acc = val;
    #pragma unroll
    for (int off = 1; off < 64; off <<= 1) {
        uint32_t o = __shfl_down(acc, off, 64);
        if (lane + off < 64) acc += o;
    }
    if (lane == 0) wsum[wid] = acc;      // wave total (suffix at lane 0)
    __syncthreads();

    uint32_t later = 0;
    for (int w = wid + 1; w < 16; ++w) later += wsum[w];
    const uint32_t sfx      = acc + later;   // sum over threads >= tid
    const uint32_t sfx_next = sfx - val;

    if (sfx >= NSEL && sfx_next < NSEL) {
        // crossing thread: refine to bucket granularity (registers only)
        int a = (int)sfx_next;
        int cut = 4 * tid;
        const uint32_t hh[4] = { h.x, h.y, h.z, h.w };
        for (int k = 3; k >= 0; --k) {
            a += (int)hh[k];
            if (a >= NSEL) { cut = 4 * tid + k; break; }
        }
        s_cut = cut;
    }
    __syncthreads();
    const uint32_t cut = (uint32_t)s_cut;

    // Collect candidates >= cut into LDS.
    const uint32_t* keys = (const uint32_t*)(ws + WS_KEYS) + (size_t)b * NQC;
    for (int i = tid; i < NQC; i += 1024) {
        uint32_t key = keys[i];
        if ((key >> 18) >= cut) {
            int pos = atomicAdd(&s_count, 1);
            if (pos < CAND_CAP) {
                cand[pos] = ((unsigned long long)key << 32)
                          | (uint32_t)(~(uint32_t)i);
            }
        }
    }
    __syncthreads();

    int count = s_count;
    if (count > CAND_CAP) count = CAND_CAP;

    float* out_scores = out;                 // [B*NSEL]
    float* out_labels = out + 600;
    float* out_boxes  = out + 1200;
    float* out_unc    = out + 3600;
    int*   sel        = (int*)(ws + WS_SEL);

    // Rank-select: rank = #candidates with larger composite key.
    // Unique keys => ranks are a permutation; rank<NSEL writes slot directly.
    // Matches descending sort with lower-index-first ties (low word = ~index).
    for (int i = tid; i < count; i += 1024) {
        const unsigned long long my = cand[i];
        int r = 0;
        for (int j = 0; j < count; ++j) r += (cand[j] > my) ? 1 : 0;
        if (r < NSEL) {
            const uint32_t key = (uint32_t)(my >> 32);
            const uint32_t idx = ~((uint32_t)(my & 0xFFFFFFFFull));
            const int q = (int)(idx / CC);
            const int label = (int)(idx - (uint32_t)q * CC);
            const int o = b * NSEL + r;

            out_scores[o] = __uint_as_float(key);
            out_labels[o] = (float)label;

            const float* bx = boxes_in + ((size_t)(b * QQ + q)) * 4;
            float cx = bx[0], cy = bx[1], w = bx[2], hgt = bx[3];
            float hh2 = (float)tsizes[b * 2 + 0];
            float ww2 = (float)tsizes[b * 2 + 1];
            out_boxes[o * 4 + 0] = (cx - 0.5f * w) * ww2;
            out_boxes[o * 4 + 1] = (cy - 0.5f * hgt) * hh2;
            out_boxes[o * 4 + 2] = (cx + 0.5f * w) * ww2;
            out_boxes[o * 4 + 3] = (cy + 0.5f * hgt) * hh2;

            const float* gv = logvars + ((size_t)(b * QQ + q)) * 4;
            float s0 = gv[0] + gv[1];
            float s1 = s0 + gv[2];
            float s2 = s1 + gv[3];
            out_unc[o] = s2 * 0.25f;

            sel[o] = q;
        }
    }
}

// ---------------- K3: bilinear upsample 128->512 + threshold ----------
// Numerics byte-identical to round-2/3 version; stores are nontemporal.
__global__ __launch_bounds__(256) void mask_kernel(
    const float* __restrict__ masks_in,  // [B,Q,128,128]
    const int*   __restrict__ sel,       // [B*NSEL]
    float* __restrict__ out_masks)       // [B*NSEL,512,512]
{
    const int m     = blockIdx.x;        // 0..599
    const int b     = m / NSEL;
    const int ytile = blockIdx.y;        // 0..7 -> 64 output rows each
    const int q     = sel[m];

    const float* src = masks_in + ((size_t)(b * QQ + q)) * (MH * MW);
    float* dst = out_masks + (size_t)m * (TGT * TGT);

    const int y0 = ytile * 64;
    int r_lo = (int)floorf((float)y0 * 0.25f - 0.375f);
    if (r_lo < 0) r_lo = 0;
    int r_hi = (int)floorf((float)(y0 + 63) * 0.25f - 0.375f) + 1;
    if (r_hi > MH - 1) r_hi = MH - 1;
    const int nrows = r_hi - r_lo + 1;   // <= 18

    __shared__ float4 S4[18 * (MW / 4)];
    float* S = (float*)S4;
    {
        const float4* src4 = (const float4*)(src + (size_t)r_lo * MW);
        const int n4 = nrows * (MW / 4);
        for (int i = threadIdx.x; i < n4; i += 256) S4[i] = src4[i];
    }
    __syncthreads();

    const int xg = threadIdx.x & 127;    // output cols 4xg..4xg+3
    const int rh = threadIdx.x >> 7;     // row half (0/1)
    const int cm1 = (xg == 0)   ? 0   : xg - 1;
    const int cp1 = (xg == 127) ? 127 : xg + 1;

    for (int i = 0; i < 32; ++i) {
        const int y = y0 + rh * 32 + i;
        float yin = (float)y * 0.25f - 0.375f;
        int r0 = (int)floorf(yin);
        float fy = yin - (float)r0;
        int r1 = r0 + 1;
        if (r0 < 0)           { r0 = 0;      r1 = 0;      fy = 0.0f; }
        else if (r1 > MH - 1) { r0 = MH - 1; r1 = MH - 1; fy = 0.0f; }
        const float wy0 = 1.0f - fy;
        const float wy1 = fy;
        const float* Ra = S + (size_t)(r0 - r_lo) * MW;
        const float* Rb = S + (size_t)(r1 - r_lo) * MW;

        float tm1 = __fadd_rn(__fmul_rn(wy0, Ra[cm1]), __fmul_rn(wy1, Rb[cm1]));
        float tc  = __fadd_rn(__fmul_rn(wy0, Ra[xg ]), __fmul_rn(wy1, Rb[xg ]));
        float tp1 = __fadd_rn(__fmul_rn(wy0, Ra[cp1]), __fmul_rn(wy1, Rb[cp1]));

        float v0, v1, v2, v3;
        if (xg == 0) {
            v0 = tc; v1 = tc;
        } else {
            v0 = __fadd_rn(__fmul_rn(0.375f, tm1), __fmul_rn(0.625f, tc));
            v1 = __fadd_rn(__fmul_rn(0.125f, tm1), __fmul_rn(0.875f, tc));
        }
        if (xg == 127) {
            v2 = tc; v3 = tc;
        } else {
            v2 = __fadd_rn(__fmul_rn(0.875f, tc), __fmul_rn(0.125f, tp1));
            v3 = __fadd_rn(__fmul_rn(0.625f, tc), __fmul_rn(0.375f, tp1));
        }

        floatx4 res;
        res.x = (v0 > 0.0f) ? 1.0f : 0.0f;
        res.y = (v1 > 0.0f) ? 1.0f : 0.0f;
        res.z = (v2 > 0.0f) ? 1.0f : 0.0f;
        res.w = (v3 > 0.0f) ? 1.0f : 0.0f;
        __builtin_nontemporal_store(res,
            reinterpret_cast<floatx4*>(&dst[(size_t)y * TGT + 4 * xg]));
    }
}

extern "C" void kernel_launch(void* const* d_in, const int* in_sizes, int n_in,
                              void* d_out, int out_size, void* d_ws, size_t ws_size,
                              hipStream_t stream) {
    (void)in_sizes; (void)n_in; (void)out_size; (void)ws_size;

    const float* pred_logits  = (const float*)d_in[0];  // [2,900,91]
    const float* pred_boxes   = (const float*)d_in[1];  // [2,900,4]
    const float* pred_masks   = (const float*)d_in[2];  // [2,900,128,128]
    const float* pred_logvars = (const float*)d_in[3];  // [2,900,4]
    const int*   target_sizes = (const int*)d_in[4];    // [2,2]

    float*   out = (float*)d_out;
    uint8_t* ws  = (uint8_t*)d_ws;

    hipLaunchKernelGGL(hist_kernel, dim3(BB * NCHUNK), dim3(256), 0, stream,
                       pred_logits, ws);
    hipLaunchKernelGGL(select_kernel, dim3(BB), dim3(1024), 0, stream,
                       pred_boxes, pred_logvars, target_sizes, out, ws);

    float* out_masks = out + 4200;
    const int* sel = (const int*)(ws + WS_SEL);
    hipLaunchKernelGGL(mask_kernel, dim3(BB * NSEL, 8), dim3(256), 0, stream,
                       pred_masks, sel, out_masks);
}